// Round 6
// baseline (538.058 us; speedup 1.0000x reference)
//
#include <hip/hip_runtime.h>
#include <hip/hip_bf16.h>

#define HEADS 8
#define DIM_HEAD 32
#define GROUPS 8
#define CCH 256            // channels
#define NTOK 4096          // d*h*w = 16^3
#define EPS 1e-5f
#define GN_SPLIT 32

// -------------------- 1a. GroupNorm partial stats --------------------
__global__ void gn_stats_partial(const float* __restrict__ x, float* __restrict__ part) {
    const int g  = blockIdx.y;
    const int sp = blockIdx.x;
    const int M = (CCH / GROUPS) * NTOK;        // 131072 contiguous floats per group
    const int chunk = M / GN_SPLIT;             // 4096
    const float4* p = (const float4*)(x + (size_t)g * M + (size_t)sp * chunk);
    float s = 0.f, ss = 0.f;
    for (int i = threadIdx.x; i < chunk / 4; i += blockDim.x) {
        float4 v = p[i];
        s  += v.x + v.y + v.z + v.w;
        ss += v.x*v.x + v.y*v.y + v.z*v.z + v.w*v.w;
    }
    #pragma unroll
    for (int off = 32; off; off >>= 1) {
        s  += __shfl_down(s,  off);
        ss += __shfl_down(ss, off);
    }
    __shared__ float sh0[8], sh1[8];
    const int wave = threadIdx.x >> 6, lane = threadIdx.x & 63;
    if (lane == 0) { sh0[wave] = s; sh1[wave] = ss; }
    __syncthreads();
    if (threadIdx.x == 0) {
        float S = 0.f, SS = 0.f;
        const int nw = blockDim.x >> 6;
        for (int w = 0; w < nw; ++w) { S += sh0[w]; SS += sh1[w]; }
        part[(g * GN_SPLIT + sp) * 2]     = S;
        part[(g * GN_SPLIT + sp) * 2 + 1] = SS;
    }
}

// -------------------- 1b. GroupNorm finalize --------------------
__global__ void gn_stats_final(const float* __restrict__ part, float* __restrict__ stats) {
    const int g = blockIdx.x;           // 8 blocks, 64 threads
    float s = 0.f, ss = 0.f;
    if (threadIdx.x < GN_SPLIT) {
        s  = part[(g * GN_SPLIT + threadIdx.x) * 2];
        ss = part[(g * GN_SPLIT + threadIdx.x) * 2 + 1];
    }
    #pragma unroll
    for (int off = 16; off; off >>= 1) {
        s  += __shfl_down(s,  off);
        ss += __shfl_down(ss, off);
    }
    if (threadIdx.x == 0) {
        const int M = (CCH / GROUPS) * NTOK;
        const float mean = s / (float)M;
        const float var  = ss / (float)M - mean * mean;
        stats[g * 2]     = mean;
        stats[g * 2 + 1] = rsqrtf(var + EPS);
    }
}

// -------------------- 2. Fold GroupNorm into QKV weights --------------------
// xn_c = x_c*(gamma_c*rstd_g) + (beta_c - mu_g*gamma_c*rstd_g)
// => qkv_o = sum_c (W[o][c]*scale_c)*x_c + (b_o + sum_c W[o][c]*shift_c)
__global__ void fold_qkv(const float* __restrict__ w, const float* __restrict__ b,
                         const float* __restrict__ gamma, const float* __restrict__ beta,
                         const float* __restrict__ stats,
                         float* __restrict__ w2, float* __restrict__ b2) {
    const int o = blockIdx.x;           // 0..767
    const int c = threadIdx.x;          // 0..255
    const int g = c >> 5;
    const float mean = stats[g * 2];
    const float rstd = stats[g * 2 + 1];
    const float sc = gamma[c] * rstd;
    const float sh = beta[c] - mean * sc;
    const float wv = w[(size_t)o * CCH + c];
    w2[(size_t)o * CCH + c] = wv * sc;
    float t = wv * sh;
    #pragma unroll
    for (int off = 32; off; off >>= 1) t += __shfl_down(t, off);
    __shared__ float shred[4];
    const int wave = threadIdx.x >> 6, lane = threadIdx.x & 63;
    if (lane == 0) shred[wave] = t;
    __syncthreads();
    if (threadIdx.x == 0)
        b2[o] = b[o] + shred[0] + shred[1] + shred[2] + shred[3];
}

// -------------------- 3. QKV GEMM, 16 outputs/thread (reads raw x, folded w/b) ----
#define QKV_OT 16
__global__ __launch_bounds__(256)
void qkv_gemm(const float* __restrict__ x, const float* __restrict__ w,
              const float* __restrict__ b, float* __restrict__ qkvt) {
    const int j  = blockIdx.x * blockDim.x + threadIdx.x;  // 0..4095
    const int ob = blockIdx.y * QKV_OT;                    // 0..767 step 16
    float acc[QKV_OT];
    #pragma unroll
    for (int u = 0; u < QKV_OT; ++u) acc[u] = b[ob + u];
    for (int c = 0; c < CCH; c += 4) {
        const float x0 = x[(size_t)(c    ) * NTOK + j];
        const float x1 = x[(size_t)(c + 1) * NTOK + j];
        const float x2 = x[(size_t)(c + 2) * NTOK + j];
        const float x3 = x[(size_t)(c + 3) * NTOK + j];
        #pragma unroll
        for (int u = 0; u < QKV_OT; ++u) {
            const float* wr = w + (size_t)(ob + u) * CCH + c;  // wave-uniform -> s_load
            acc[u] = fmaf(wr[0], x0, acc[u]);
            acc[u] = fmaf(wr[1], x1, acc[u]);
            acc[u] = fmaf(wr[2], x2, acc[u]);
            acc[u] = fmaf(wr[3], x3, acc[u]);
        }
    }
    const int part = ob >> 8;
    const int h    = (ob & 255) >> 5;
    const int dbase = ob & 31;          // 0 or 16
    float* dst = qkvt + (((size_t)part * HEADS + h) * NTOK + j) * DIM_HEAD + dbase;
    #pragma unroll
    for (int u = 0; u < QKV_OT; u += 4) {
        float4 t;
        t.x = acc[u]; t.y = acc[u+1]; t.z = acc[u+2]; t.w = acc[u+3];
        *(float4*)(dst + u) = t;
    }
}

// -------------------- 4. Attention partial: LDS-staged K/V, double-buffered ------
// R5 lesson: effective VGPR pool ~= 256/SIMD (R2: 32reg->6.2 w/SIMD; R3-5: 56reg->3.2,
// grid-independent). 8 waves/SIMD unreachable with q[32]+acc[32]. Instead remove the
// SMEM-latency stalls: K/V tiles are shared by the whole block -> stage in LDS
// (reg-staged dbuf; next-tile global loads issued before compute -> latency hidden).
// Inner reads are broadcast ds_read_b128 (all lanes same addr, conflict-free).
#define TJ 64          // j rows per LDS tile
#define JB 8           // softmax blocking
__global__ __launch_bounds__(256)
__attribute__((amdgpu_waves_per_eu(2, 8)))
void attn_partial(const float* __restrict__ qkvt,
                  float* __restrict__ pm, float* __restrict__ pl,
                  float* __restrict__ pacc, const int jlen) {
    const int tid = threadIdx.x;
    const int i = blockIdx.x * blockDim.x + tid;           // query index
    const int h = blockIdx.y;
    const int s = blockIdx.z;
    const int js = gridDim.z;

    __shared__ __align__(16) float lk[2][TJ * DIM_HEAD];   // 2 x 8 KB
    __shared__ __align__(16) float lv[2][TJ * DIM_HEAD];   // 2 x 8 KB

    const float* qp = qkvt + ((size_t)h * NTOK + i) * DIM_HEAD;
    float q[DIM_HEAD];
    #pragma unroll
    for (int d0 = 0; d0 < DIM_HEAD; d0 += 4) {
        float4 t = *(const float4*)(qp + d0);
        q[d0] = t.x; q[d0+1] = t.y; q[d0+2] = t.z; q[d0+3] = t.w;
    }
    const float scale = 0.17677669529663687f;  // 32^-0.5
    float m = -1e30f, l = 0.f;
    float acc[DIM_HEAD];
    #pragma unroll
    for (int d = 0; d < DIM_HEAD; ++d) acc[d] = 0.f;

    const float* kbase = qkvt + (size_t)(HEADS + h)     * NTOK * DIM_HEAD
                       + (size_t)(s * jlen) * DIM_HEAD;
    const float* vbase = qkvt + (size_t)(2 * HEADS + h) * NTOK * DIM_HEAD
                       + (size_t)(s * jlen) * DIM_HEAD;

    const int ntiles = jlen / TJ;
    // tile = TJ*32 = 2048 floats = 512 float4; 256 threads stage 2 float4 each (K and V)
    float4 k0 = *(const float4*)(kbase + tid * 4);
    float4 k1 = *(const float4*)(kbase + 1024 + tid * 4);
    float4 v0 = *(const float4*)(vbase + tid * 4);
    float4 v1 = *(const float4*)(vbase + 1024 + tid * 4);

    int cur = 0;
    for (int t = 0; t < ntiles; ++t) {
        __syncthreads();                      // prev compute done: buffer cur free
        ((float4*)lk[cur])[tid]       = k0;
        ((float4*)lk[cur])[256 + tid] = k1;
        ((float4*)lv[cur])[tid]       = v0;
        ((float4*)lv[cur])[256 + tid] = v1;
        if (t + 1 < ntiles) {                 // issue next-tile loads; hide under compute
            const float* kn = kbase + (size_t)(t + 1) * TJ * DIM_HEAD;
            const float* vn = vbase + (size_t)(t + 1) * TJ * DIM_HEAD;
            k0 = *(const float4*)(kn + tid * 4);
            k1 = *(const float4*)(kn + 1024 + tid * 4);
            v0 = *(const float4*)(vn + tid * 4);
            v1 = *(const float4*)(vn + 1024 + tid * 4);
        }
        __syncthreads();                      // lds tile visible
        const float* lkc = lk[cur];
        const float* lvc = lv[cur];
        #pragma unroll
        for (int jb = 0; jb < TJ; jb += JB) {
            // ---- JB scores (broadcast ds_read_b128) ----
            float sc[JB];
            #pragma unroll
            for (int u = 0; u < JB; ++u) {
                const float* kp = lkc + (jb + u) * DIM_HEAD;
                float s0 = 0.f, s1 = 0.f, s2 = 0.f, s3 = 0.f;
                #pragma unroll
                for (int d0 = 0; d0 < DIM_HEAD; d0 += 4) {
                    float4 kv = *(const float4*)(kp + d0);
                    s0 = fmaf(q[d0],   kv.x, s0);
                    s1 = fmaf(q[d0+1], kv.y, s1);
                    s2 = fmaf(q[d0+2], kv.z, s2);
                    s3 = fmaf(q[d0+3], kv.w, s3);
                }
                sc[u] = (s0 + s1 + s2 + s3) * scale;
            }
            // ---- block max + single branchless rescale ----
            float bm = sc[0];
            #pragma unroll
            for (int u = 1; u < JB; ++u) bm = fmaxf(bm, sc[u]);
            const float mn = fmaxf(m, bm);
            const float corr = __expf(m - mn);
            m = mn;
            l *= corr;
            #pragma unroll
            for (int d = 0; d < DIM_HEAD; ++d) acc[d] *= corr;
            // ---- probabilities ----
            float p[JB];
            #pragma unroll
            for (int u = 0; u < JB; ++u) { p[u] = __expf(sc[u] - m); l += p[u]; }
            // ---- PV rank-1 updates ----
            #pragma unroll
            for (int u = 0; u < JB; ++u) {
                const float* vp = lvc + (jb + u) * DIM_HEAD;
                #pragma unroll
                for (int d0 = 0; d0 < DIM_HEAD; d0 += 4) {
                    float4 vv = *(const float4*)(vp + d0);
                    acc[d0]   = fmaf(p[u], vv.x, acc[d0]);
                    acc[d0+1] = fmaf(p[u], vv.y, acc[d0+1]);
                    acc[d0+2] = fmaf(p[u], vv.z, acc[d0+2]);
                    acc[d0+3] = fmaf(p[u], vv.w, acc[d0+3]);
                }
            }
        }
        cur ^= 1;
    }
    const size_t pidx = ((size_t)(h * js + s) * NTOK + i);
    pm[pidx] = m;
    pl[pidx] = l;
    float* pa = pacc + pidx * DIM_HEAD;
    #pragma unroll
    for (int d0 = 0; d0 < DIM_HEAD; d0 += 4) {
        float4 t;
        t.x = acc[d0]; t.y = acc[d0+1]; t.z = acc[d0+2]; t.w = acc[d0+3];
        *(float4*)(pa + d0) = t;
    }
}

// -------------------- 5. Combine partial softmax states (compile-time JS) --------------------
template <int JS>
__global__ void attn_combine(const float* __restrict__ pm, const float* __restrict__ pl,
                             const float* __restrict__ pacc, float* __restrict__ att) {
    const int i = blockIdx.x * blockDim.x + threadIdx.x;   // 0..4095
    const int h = blockIdx.y;
    float mv[JS], lv[JS];
    float mM = -1e30f;
    #pragma unroll
    for (int s = 0; s < JS; ++s) {
        const size_t pidx = ((size_t)(h * JS + s) * NTOK + i);
        mv[s] = pm[pidx];
        lv[s] = pl[pidx];
        mM = fmaxf(mM, mv[s]);
    }
    float wv[JS];
    float denom = 0.f;
    #pragma unroll
    for (int s = 0; s < JS; ++s) {
        wv[s] = __expf(mv[s] - mM);
        denom += lv[s] * wv[s];
    }
    const float inv = 1.f / denom;
    #pragma unroll
    for (int d0 = 0; d0 < DIM_HEAD; d0 += 4) {
        float o0 = 0.f, o1 = 0.f, o2 = 0.f, o3 = 0.f;
        #pragma unroll
        for (int s = 0; s < JS; ++s) {
            const size_t pidx = ((size_t)(h * JS + s) * NTOK + i);
            float4 a = *(const float4*)(pacc + pidx * DIM_HEAD + d0);
            o0 = fmaf(a.x, wv[s], o0);
            o1 = fmaf(a.y, wv[s], o1);
            o2 = fmaf(a.z, wv[s], o2);
            o3 = fmaf(a.w, wv[s], o3);
        }
        att[(size_t)(h * DIM_HEAD + d0    ) * NTOK + i] = o0 * inv;
        att[(size_t)(h * DIM_HEAD + d0 + 1) * NTOK + i] = o1 * inv;
        att[(size_t)(h * DIM_HEAD + d0 + 2) * NTOK + i] = o2 * inv;
        att[(size_t)(h * DIM_HEAD + d0 + 3) * NTOK + i] = o3 * inv;
    }
}

// -------------------- 6. Output projection, 8 outputs/thread --------------------
#define OUT_OT 8
__global__ __launch_bounds__(256)
void out_proj(const float* __restrict__ att, const float* __restrict__ w,
              const float* __restrict__ b, const float* __restrict__ x,
              float* __restrict__ out) {
    const int j  = blockIdx.x * blockDim.x + threadIdx.x;  // 0..4095
    const int ob = blockIdx.y * OUT_OT;                    // 0..255 step 8
    float acc[OUT_OT];
    #pragma unroll
    for (int u = 0; u < OUT_OT; ++u) acc[u] = b[ob + u];
    for (int c = 0; c < CCH; c += 4) {
        const float a0 = att[(size_t)(c    ) * NTOK + j];
        const float a1 = att[(size_t)(c + 1) * NTOK + j];
        const float a2 = att[(size_t)(c + 2) * NTOK + j];
        const float a3 = att[(size_t)(c + 3) * NTOK + j];
        #pragma unroll
        for (int u = 0; u < OUT_OT; ++u) {
            const float* wr = w + (size_t)(ob + u) * CCH + c;  // wave-uniform -> s_load
            acc[u] = fmaf(wr[0], a0, acc[u]);
            acc[u] = fmaf(wr[1], a1, acc[u]);
            acc[u] = fmaf(wr[2], a2, acc[u]);
            acc[u] = fmaf(wr[3], a3, acc[u]);
        }
    }
    #pragma unroll
    for (int u = 0; u < OUT_OT; ++u) {
        const size_t idx = (size_t)(ob + u) * NTOK + j;
        out[idx] = acc[u] + x[idx];
    }
}

extern "C" void kernel_launch(void* const* d_in, const int* in_sizes, int n_in,
                              void* d_out, int out_size, void* d_ws, size_t ws_size,
                              hipStream_t stream) {
    const float* x     = (const float*)d_in[0];
    const float* gamma = (const float*)d_in[1];
    const float* beta  = (const float*)d_in[2];
    const float* w_qkv = (const float*)d_in[3];
    const float* b_qkv = (const float*)d_in[4];
    const float* w_out = (const float*)d_in[5];
    const float* b_out = (const float*)d_in[6];
    float* out = (float*)d_out;

    float* ws    = (float*)d_ws;
    float* stats = ws;                          // 64
    float* part  = stats + 64;                  // 512
    float* w2    = part  + 512;                 // 768*256 = 196608 (in old xn slot)
    float* b2    = w2    + 196608;              // 768
    float* qkvt  = part  + 512 + 1048576;       // keep old offset for capacity math
    float* pm    = qkvt  + (size_t)3 * CCH * NTOK;

    // j-split from workspace (16 -> 8 -> 4)
    int js = 4;
    {
        const size_t base = 64 + 512 + (size_t)CCH * NTOK + (size_t)3 * CCH * NTOK;
        for (int cand = 16; cand >= 8; cand >>= 1) {
            const size_t need = base
                + (size_t)HEADS * cand * NTOK * (2 + DIM_HEAD)
                + (size_t)CCH * NTOK;
            if (need * sizeof(float) <= ws_size) { js = cand; break; }
        }
    }
    const int jlen = NTOK / js;

    float* pl   = pm   + (size_t)HEADS * js * NTOK;
    float* pacc = pl   + (size_t)HEADS * js * NTOK;
    float* att  = pacc + (size_t)HEADS * js * NTOK * DIM_HEAD;

    {
        dim3 g(GN_SPLIT, GROUPS);
        gn_stats_partial<<<g, 256, 0, stream>>>(x, part);
    }
    gn_stats_final<<<GROUPS, 64, 0, stream>>>(part, stats);
    fold_qkv<<<3 * CCH, 256, 0, stream>>>(w_qkv, b_qkv, gamma, beta, stats, w2, b2);
    {
        dim3 g(NTOK / 256, 3 * CCH / QKV_OT);
        qkv_gemm<<<g, 256, 0, stream>>>(x, w2, b2, qkvt);
    }
    {
        dim3 g(NTOK / 256, HEADS, js);
        attn_partial<<<g, 256, 0, stream>>>(qkvt, pm, pl, pacc, jlen);
    }
    {
        dim3 g(NTOK / 256, HEADS);
        if (js == 16)      attn_combine<16><<<g, 256, 0, stream>>>(pm, pl, pacc, att);
        else if (js == 8)  attn_combine<8><<<g, 256, 0, stream>>>(pm, pl, pacc, att);
        else               attn_combine<4><<<g, 256, 0, stream>>>(pm, pl, pacc, att);
    }
    {
        dim3 g(NTOK / 256, CCH / OUT_OT);
        out_proj<<<g, 256, 0, stream>>>(att, w_out, b_out, x, out);
    }
}

// Round 7
// 194.111 us; speedup vs baseline: 2.7719x; 2.7719x over previous
//
#include <hip/hip_runtime.h>
#include <hip/hip_bf16.h>

#define HEADS 8
#define DIM_HEAD 32
#define GROUPS 8
#define CCH 256            // channels
#define NTOK 4096          // d*h*w = 16^3
#define EPS 1e-5f
#define GN_SPLIT 32

typedef _Float16 half8 __attribute__((ext_vector_type(8)));
typedef float f32x4 __attribute__((ext_vector_type(4)));

// -------------------- 1a. GroupNorm partial stats --------------------
__global__ void gn_stats_partial(const float* __restrict__ x, float* __restrict__ part) {
    const int g  = blockIdx.y;
    const int sp = blockIdx.x;
    const int M = (CCH / GROUPS) * NTOK;        // 131072 contiguous floats per group
    const int chunk = M / GN_SPLIT;             // 4096
    const float4* p = (const float4*)(x + (size_t)g * M + (size_t)sp * chunk);
    float s = 0.f, ss = 0.f;
    for (int i = threadIdx.x; i < chunk / 4; i += blockDim.x) {
        float4 v = p[i];
        s  += v.x + v.y + v.z + v.w;
        ss += v.x*v.x + v.y*v.y + v.z*v.z + v.w*v.w;
    }
    #pragma unroll
    for (int off = 32; off; off >>= 1) {
        s  += __shfl_down(s,  off);
        ss += __shfl_down(ss, off);
    }
    __shared__ float sh0[8], sh1[8];
    const int wave = threadIdx.x >> 6, lane = threadIdx.x & 63;
    if (lane == 0) { sh0[wave] = s; sh1[wave] = ss; }
    __syncthreads();
    if (threadIdx.x == 0) {
        float S = 0.f, SS = 0.f;
        const int nw = blockDim.x >> 6;
        for (int w = 0; w < nw; ++w) { S += sh0[w]; SS += sh1[w]; }
        part[(g * GN_SPLIT + sp) * 2]     = S;
        part[(g * GN_SPLIT + sp) * 2 + 1] = SS;
    }
}

// -------------------- 1b. GroupNorm finalize --------------------
__global__ void gn_stats_final(const float* __restrict__ part, float* __restrict__ stats) {
    const int g = blockIdx.x;           // 8 blocks, 64 threads
    float s = 0.f, ss = 0.f;
    if (threadIdx.x < GN_SPLIT) {
        s  = part[(g * GN_SPLIT + threadIdx.x) * 2];
        ss = part[(g * GN_SPLIT + threadIdx.x) * 2 + 1];
    }
    #pragma unroll
    for (int off = 16; off; off >>= 1) {
        s  += __shfl_down(s,  off);
        ss += __shfl_down(ss, off);
    }
    if (threadIdx.x == 0) {
        const int M = (CCH / GROUPS) * NTOK;
        const float mean = s / (float)M;
        const float var  = ss / (float)M - mean * mean;
        stats[g * 2]     = mean;
        stats[g * 2 + 1] = rsqrtf(var + EPS);
    }
}

// -------------------- 2. Fold GroupNorm into QKV weights --------------------
__global__ void fold_qkv(const float* __restrict__ w, const float* __restrict__ b,
                         const float* __restrict__ gamma, const float* __restrict__ beta,
                         const float* __restrict__ stats,
                         float* __restrict__ w2, float* __restrict__ b2) {
    const int o = blockIdx.x;           // 0..767
    const int c = threadIdx.x;          // 0..255
    const int g = c >> 5;
    const float mean = stats[g * 2];
    const float rstd = stats[g * 2 + 1];
    const float sc = gamma[c] * rstd;
    const float sh = beta[c] - mean * sc;
    const float wv = w[(size_t)o * CCH + c];
    w2[(size_t)o * CCH + c] = wv * sc;
    float t = wv * sh;
    #pragma unroll
    for (int off = 32; off; off >>= 1) t += __shfl_down(t, off);
    __shared__ float shred[4];
    const int wave = threadIdx.x >> 6, lane = threadIdx.x & 63;
    if (lane == 0) shred[wave] = t;
    __syncthreads();
    if (threadIdx.x == 0)
        b2[o] = b[o] + shred[0] + shred[1] + shred[2] + shred[3];
}

// -------------------- 3. QKV GEMM, fp32 compute, fp16 outputs ----------------
// q_h[h][i][d] (pre-scaled by 32^-0.5), k_h[h][j][d], vT_h[h][d][j].
#define QKV_OT 16
__global__ __launch_bounds__(256)
void qkv_gemm(const float* __restrict__ x, const float* __restrict__ w,
              const float* __restrict__ b,
              _Float16* __restrict__ q_h, _Float16* __restrict__ k_h,
              _Float16* __restrict__ vT_h) {
    const int j  = blockIdx.x * blockDim.x + threadIdx.x;  // 0..4095
    const int ob = blockIdx.y * QKV_OT;                    // 0..767 step 16
    float acc[QKV_OT];
    #pragma unroll
    for (int u = 0; u < QKV_OT; ++u) acc[u] = b[ob + u];
    for (int c = 0; c < CCH; c += 4) {
        const float x0 = x[(size_t)(c    ) * NTOK + j];
        const float x1 = x[(size_t)(c + 1) * NTOK + j];
        const float x2 = x[(size_t)(c + 2) * NTOK + j];
        const float x3 = x[(size_t)(c + 3) * NTOK + j];
        #pragma unroll
        for (int u = 0; u < QKV_OT; ++u) {
            const float* wr = w + (size_t)(ob + u) * CCH + c;  // wave-uniform -> s_load
            acc[u] = fmaf(wr[0], x0, acc[u]);
            acc[u] = fmaf(wr[1], x1, acc[u]);
            acc[u] = fmaf(wr[2], x2, acc[u]);
            acc[u] = fmaf(wr[3], x3, acc[u]);
        }
    }
    const int part  = ob >> 8;
    const int h     = (ob & 255) >> 5;
    const int dbase = ob & 31;          // 0 or 16
    if (part == 0) {
        const float scale = 0.17677669529663687f;  // 32^-0.5 baked into Q
        __attribute__((aligned(16))) _Float16 hv[QKV_OT];
        #pragma unroll
        for (int u = 0; u < QKV_OT; ++u) hv[u] = (_Float16)(acc[u] * scale);
        uint4* dst = (uint4*)(q_h + ((size_t)h * NTOK + j) * DIM_HEAD + dbase);
        dst[0] = ((const uint4*)hv)[0];
        dst[1] = ((const uint4*)hv)[1];
    } else if (part == 1) {
        __attribute__((aligned(16))) _Float16 hv[QKV_OT];
        #pragma unroll
        for (int u = 0; u < QKV_OT; ++u) hv[u] = (_Float16)acc[u];
        uint4* dst = (uint4*)(k_h + ((size_t)h * NTOK + j) * DIM_HEAD + dbase);
        dst[0] = ((const uint4*)hv)[0];
        dst[1] = ((const uint4*)hv)[1];
    } else {
        // V stored transposed: vT[h][d][j]; per-u stores are 2B/lane, coalesced in j.
        #pragma unroll
        for (int u = 0; u < QKV_OT; ++u)
            vT_h[((size_t)h * DIM_HEAD + dbase + u) * NTOK + j] = (_Float16)acc[u];
    }
}

// -------------------- 4. Flash attention, fp16 MFMA, fp32 accum --------------
// Block = 4 waves; wave owns 16 queries; iterates all 4096 j in 64-j tiles.
// Fragment layouts follow the m91/m97-verified pattern:
//   A: lane holds row (lane&15), k = (lane>>4)*8 .. +7 (contiguous)
//   B: fed from row-major "B^T" rows the same way
//   D: row = (lane>>4)*4 + reg, col = lane&15
#define TJ 64
#define VPAD 72     // Vt / P LDS row stride in halves (bank-balance padding)
__global__ __launch_bounds__(256)
void attn_mfma(const _Float16* __restrict__ q_h, const _Float16* __restrict__ k_h,
               const _Float16* __restrict__ vT_h, float* __restrict__ att) {
    const int tid = threadIdx.x;
    const int w = tid >> 6, lane = tid & 63;
    const int la = lane & 15, lg = lane >> 4;
    const int h = blockIdx.y;
    const int qbase = blockIdx.x * 64 + w * 16;

    __shared__ _Float16 lk [2][TJ * DIM_HEAD];       // K tile, rows of 32 halves (64B)
    __shared__ _Float16 lvt[2][DIM_HEAD * VPAD];     // V^T tile, rows of 72 halves
    __shared__ _Float16 plds[4][16 * VPAD];          // per-wave P tile

    // Q A-fragment (row la, dims lg*8..+7), scale pre-baked
    const half8 aq = *(const half8*)(q_h + ((size_t)h * NTOK + qbase + la) * DIM_HEAD + lg * 8);

    f32x4 acc0 = {0.f, 0.f, 0.f, 0.f};
    f32x4 acc1 = {0.f, 0.f, 0.f, 0.f};
    float mrow[4] = {-1e30f, -1e30f, -1e30f, -1e30f};
    float lrow[4] = {0.f, 0.f, 0.f, 0.f};

    const _Float16* kg = k_h  + (size_t)h * NTOK * DIM_HEAD;
    const _Float16* vg = vT_h + (size_t)h * DIM_HEAD * NTOK;
    const int vrow = tid >> 3, vseg = tid & 7;       // staging coords for V^T

    uint4 kreg, vreg;
    // prologue: tile 0 into buf0, tile 1 into regs
    kreg = ((const uint4*)kg)[tid];
    vreg = *(const uint4*)(vg + (size_t)vrow * NTOK + vseg * 8);
    ((uint4*)lk[0])[tid] = kreg;
    *(uint4*)&lvt[0][vrow * VPAD + vseg * 8] = vreg;
    kreg = ((const uint4*)(kg + (size_t)TJ * DIM_HEAD))[tid];
    vreg = *(const uint4*)(vg + (size_t)vrow * NTOK + TJ + vseg * 8);
    __syncthreads();

    const int NT = NTOK / TJ;     // 64
    for (int t = 0; t < NT; ++t) {
        const int cur = t & 1;
        if (t + 1 < NT) {
            ((uint4*)lk[cur ^ 1])[tid] = kreg;
            *(uint4*)&lvt[cur ^ 1][vrow * VPAD + vseg * 8] = vreg;
            if (t + 2 < NT) {
                kreg = ((const uint4*)(kg + (size_t)(t + 2) * TJ * DIM_HEAD))[tid];
                vreg = *(const uint4*)(vg + (size_t)vrow * NTOK + (t + 2) * TJ + vseg * 8);
            }
        }
        // ---- QK^T: 4 sub-tiles of 16 keys, K=32 in one MFMA each ----
        f32x4 sc[4];
        #pragma unroll
        for (int sub = 0; sub < 4; ++sub) {
            const half8 bk = *(const half8*)&lk[cur][(sub * 16 + la) * DIM_HEAD + lg * 8];
            f32x4 z = {0.f, 0.f, 0.f, 0.f};
            sc[sub] = __builtin_amdgcn_mfma_f32_16x16x32_f16(aq, bk, z, 0, 0, 0);
        }
        // ---- online softmax (rows = q = lg*4+r; reduce over la via shfl_xor) ----
        #pragma unroll
        for (int r = 0; r < 4; ++r) {
            float tm = fmaxf(fmaxf(sc[0][r], sc[1][r]), fmaxf(sc[2][r], sc[3][r]));
            #pragma unroll
            for (int msk = 8; msk; msk >>= 1) tm = fmaxf(tm, __shfl_xor(tm, msk));
            const float mn   = fmaxf(mrow[r], tm);
            const float corr = __expf(mrow[r] - mn);
            mrow[r] = mn;
            lrow[r] *= corr;
            acc0[r] *= corr;
            acc1[r] *= corr;
            float ps = 0.f;
            #pragma unroll
            for (int sub = 0; sub < 4; ++sub) {
                const float p = __expf(sc[sub][r] - mn);
                ps += p;
                plds[w][(lg * 4 + r) * VPAD + sub * 16 + la] = (_Float16)p;
            }
            lrow[r] += ps;   // per-lane partial over this lane's key columns
        }
        // ---- PV: out[16q][32d] += P[16q][64k] * V[64k][32d] ----
        #pragma unroll
        for (int kc = 0; kc < 2; ++kc) {
            const half8 pa = *(const half8*)&plds[w][la * VPAD + kc * 32 + lg * 8];
            const half8 v0 = *(const half8*)&lvt[cur][(la     ) * VPAD + kc * 32 + lg * 8];
            const half8 v1 = *(const half8*)&lvt[cur][(la + 16) * VPAD + kc * 32 + lg * 8];
            acc0 = __builtin_amdgcn_mfma_f32_16x16x32_f16(pa, v0, acc0, 0, 0, 0);
            acc1 = __builtin_amdgcn_mfma_f32_16x16x32_f16(pa, v1, acc1, 0, 0, 0);
        }
        __syncthreads();
    }
    // ---- finalize: reduce l across the 16-lane group, scale, store ----
    #pragma unroll
    for (int r = 0; r < 4; ++r) {
        float lt = lrow[r];
        #pragma unroll
        for (int msk = 8; msk; msk >>= 1) lt += __shfl_xor(lt, msk);
        const float inv = 1.f / lt;
        const int iq = qbase + lg * 4 + r;
        att[((size_t)h * DIM_HEAD + la     ) * NTOK + iq] = acc0[r] * inv;
        att[((size_t)h * DIM_HEAD + la + 16) * NTOK + iq] = acc1[r] * inv;
    }
}

// -------------------- 6. Output projection, 8 outputs/thread --------------------
#define OUT_OT 8
__global__ __launch_bounds__(256)
void out_proj(const float* __restrict__ att, const float* __restrict__ w,
              const float* __restrict__ b, const float* __restrict__ x,
              float* __restrict__ out) {
    const int j  = blockIdx.x * blockDim.x + threadIdx.x;  // 0..4095
    const int ob = blockIdx.y * OUT_OT;                    // 0..255 step 8
    float acc[OUT_OT];
    #pragma unroll
    for (int u = 0; u < OUT_OT; ++u) acc[u] = b[ob + u];
    for (int c = 0; c < CCH; c += 4) {
        const float a0 = att[(size_t)(c    ) * NTOK + j];
        const float a1 = att[(size_t)(c + 1) * NTOK + j];
        const float a2 = att[(size_t)(c + 2) * NTOK + j];
        const float a3 = att[(size_t)(c + 3) * NTOK + j];
        #pragma unroll
        for (int u = 0; u < OUT_OT; ++u) {
            const float* wr = w + (size_t)(ob + u) * CCH + c;  // wave-uniform -> s_load
            acc[u] = fmaf(wr[0], a0, acc[u]);
            acc[u] = fmaf(wr[1], a1, acc[u]);
            acc[u] = fmaf(wr[2], a2, acc[u]);
            acc[u] = fmaf(wr[3], a3, acc[u]);
        }
    }
    #pragma unroll
    for (int u = 0; u < OUT_OT; ++u) {
        const size_t idx = (size_t)(ob + u) * NTOK + j;
        out[idx] = acc[u] + x[idx];
    }
}

extern "C" void kernel_launch(void* const* d_in, const int* in_sizes, int n_in,
                              void* d_out, int out_size, void* d_ws, size_t ws_size,
                              hipStream_t stream) {
    const float* x     = (const float*)d_in[0];
    const float* gamma = (const float*)d_in[1];
    const float* beta  = (const float*)d_in[2];
    const float* w_qkv = (const float*)d_in[3];
    const float* b_qkv = (const float*)d_in[4];
    const float* w_out = (const float*)d_in[5];
    const float* b_out = (const float*)d_in[6];
    float* out = (float*)d_out;

    float* ws    = (float*)d_ws;
    float* stats = ws;                          // 64
    float* part  = stats + 64;                  // 512
    float* w2    = part  + 512;                 // 768*256 = 196608
    float* b2    = w2    + 196608;              // 768
    float* att   = b2    + 768;                 // 256*4096 = 1048576 (fp32)
    _Float16* q_h  = (_Float16*)(att + 1048576);           // 8*4096*32 halves (2MB)
    _Float16* k_h  = q_h + (size_t)HEADS * NTOK * DIM_HEAD;
    _Float16* vT_h = k_h + (size_t)HEADS * NTOK * DIM_HEAD;
    // total ~11.3 MB (ws proven >= 92 MB in round 2)

    {
        dim3 g(GN_SPLIT, GROUPS);
        gn_stats_partial<<<g, 256, 0, stream>>>(x, part);
    }
    gn_stats_final<<<GROUPS, 64, 0, stream>>>(part, stats);
    fold_qkv<<<3 * CCH, 256, 0, stream>>>(w_qkv, b_qkv, gamma, beta, stats, w2, b2);
    {
        dim3 g(NTOK / 256, 3 * CCH / QKV_OT);
        qkv_gemm<<<g, 256, 0, stream>>>(x, w2, b2, q_h, k_h, vT_h);
    }
    {
        dim3 g(NTOK / 64, HEADS);
        attn_mfma<<<g, 256, 0, stream>>>(q_h, k_h, vT_h, att);
    }
    {
        dim3 g(NTOK / 256, CCH / OUT_OT);
        out_proj<<<g, 256, 0, stream>>>(att, w_out, b_out, x, out);
    }
}

// Round 8
// 156.673 us; speedup vs baseline: 3.4343x; 1.2390x over previous
//
#include <hip/hip_runtime.h>
#include <hip/hip_bf16.h>

#define HEADS 8
#define DIM_HEAD 32
#define GROUPS 8
#define CCH 256            // channels
#define NTOK 4096          // d*h*w = 16^3
#define EPS 1e-5f
#define GN_SPLIT 32
#define JS 4               // attention j-split (occupancy)

typedef _Float16 half8 __attribute__((ext_vector_type(8)));
typedef float f32x4 __attribute__((ext_vector_type(4)));

// -------------------- 1a. GroupNorm partial stats --------------------
__global__ void gn_stats_partial(const float* __restrict__ x, float* __restrict__ part) {
    const int g  = blockIdx.y;
    const int sp = blockIdx.x;
    const int M = (CCH / GROUPS) * NTOK;        // 131072 contiguous floats per group
    const int chunk = M / GN_SPLIT;             // 4096
    const float4* p = (const float4*)(x + (size_t)g * M + (size_t)sp * chunk);
    float s = 0.f, ss = 0.f;
    for (int i = threadIdx.x; i < chunk / 4; i += blockDim.x) {
        float4 v = p[i];
        s  += v.x + v.y + v.z + v.w;
        ss += v.x*v.x + v.y*v.y + v.z*v.z + v.w*v.w;
    }
    #pragma unroll
    for (int off = 32; off; off >>= 1) {
        s  += __shfl_down(s,  off);
        ss += __shfl_down(ss, off);
    }
    __shared__ float sh0[8], sh1[8];
    const int wave = threadIdx.x >> 6, lane = threadIdx.x & 63;
    if (lane == 0) { sh0[wave] = s; sh1[wave] = ss; }
    __syncthreads();
    if (threadIdx.x == 0) {
        float S = 0.f, SS = 0.f;
        const int nw = blockDim.x >> 6;
        for (int w = 0; w < nw; ++w) { S += sh0[w]; SS += sh1[w]; }
        part[(g * GN_SPLIT + sp) * 2]     = S;
        part[(g * GN_SPLIT + sp) * 2 + 1] = SS;
    }
}

// -------------------- 1b. GroupNorm finalize --------------------
__global__ void gn_stats_final(const float* __restrict__ part, float* __restrict__ stats) {
    const int g = blockIdx.x;           // 8 blocks, 64 threads
    float s = 0.f, ss = 0.f;
    if (threadIdx.x < GN_SPLIT) {
        s  = part[(g * GN_SPLIT + threadIdx.x) * 2];
        ss = part[(g * GN_SPLIT + threadIdx.x) * 2 + 1];
    }
    #pragma unroll
    for (int off = 16; off; off >>= 1) {
        s  += __shfl_down(s,  off);
        ss += __shfl_down(ss, off);
    }
    if (threadIdx.x == 0) {
        const int M = (CCH / GROUPS) * NTOK;
        const float mean = s / (float)M;
        const float var  = ss / (float)M - mean * mean;
        stats[g * 2]     = mean;
        stats[g * 2 + 1] = rsqrtf(var + EPS);
    }
}

// -------------------- 2. Fold GroupNorm into QKV weights --------------------
__global__ void fold_qkv(const float* __restrict__ w, const float* __restrict__ b,
                         const float* __restrict__ gamma, const float* __restrict__ beta,
                         const float* __restrict__ stats,
                         float* __restrict__ w2, float* __restrict__ b2) {
    const int o = blockIdx.x;           // 0..767
    const int c = threadIdx.x;          // 0..255
    const int g = c >> 5;
    const float mean = stats[g * 2];
    const float rstd = stats[g * 2 + 1];
    const float sc = gamma[c] * rstd;
    const float sh = beta[c] - mean * sc;
    const float wv = w[(size_t)o * CCH + c];
    w2[(size_t)o * CCH + c] = wv * sc;
    float t = wv * sh;
    #pragma unroll
    for (int off = 32; off; off >>= 1) t += __shfl_down(t, off);
    __shared__ float shred[4];
    const int wave = threadIdx.x >> 6, lane = threadIdx.x & 63;
    if (lane == 0) shred[wave] = t;
    __syncthreads();
    if (threadIdx.x == 0)
        b2[o] = b[o] + shred[0] + shred[1] + shred[2] + shred[3];
}

// -------------------- 3. QKV GEMM, fp32 compute, fp16 outputs ----------------
// q_h[h][i][d] (pre-scaled by 32^-0.5), k_h[h][j][d], vT_h[h][d][j].
#define QKV_OT 16
__global__ __launch_bounds__(256)
void qkv_gemm(const float* __restrict__ x, const float* __restrict__ w,
              const float* __restrict__ b,
              _Float16* __restrict__ q_h, _Float16* __restrict__ k_h,
              _Float16* __restrict__ vT_h) {
    const int j  = blockIdx.x * blockDim.x + threadIdx.x;  // 0..4095
    const int ob = blockIdx.y * QKV_OT;                    // 0..767 step 16
    float acc[QKV_OT];
    #pragma unroll
    for (int u = 0; u < QKV_OT; ++u) acc[u] = b[ob + u];
    for (int c = 0; c < CCH; c += 4) {
        const float x0 = x[(size_t)(c    ) * NTOK + j];
        const float x1 = x[(size_t)(c + 1) * NTOK + j];
        const float x2 = x[(size_t)(c + 2) * NTOK + j];
        const float x3 = x[(size_t)(c + 3) * NTOK + j];
        #pragma unroll
        for (int u = 0; u < QKV_OT; ++u) {
            const float* wr = w + (size_t)(ob + u) * CCH + c;  // wave-uniform -> s_load
            acc[u] = fmaf(wr[0], x0, acc[u]);
            acc[u] = fmaf(wr[1], x1, acc[u]);
            acc[u] = fmaf(wr[2], x2, acc[u]);
            acc[u] = fmaf(wr[3], x3, acc[u]);
        }
    }
    const int part  = ob >> 8;
    const int h     = (ob & 255) >> 5;
    const int dbase = ob & 31;          // 0 or 16
    if (part == 0) {
        const float scale = 0.17677669529663687f;  // 32^-0.5 baked into Q
        __attribute__((aligned(16))) _Float16 hv[QKV_OT];
        #pragma unroll
        for (int u = 0; u < QKV_OT; ++u) hv[u] = (_Float16)(acc[u] * scale);
        uint4* dst = (uint4*)(q_h + ((size_t)h * NTOK + j) * DIM_HEAD + dbase);
        dst[0] = ((const uint4*)hv)[0];
        dst[1] = ((const uint4*)hv)[1];
    } else if (part == 1) {
        __attribute__((aligned(16))) _Float16 hv[QKV_OT];
        #pragma unroll
        for (int u = 0; u < QKV_OT; ++u) hv[u] = (_Float16)acc[u];
        uint4* dst = (uint4*)(k_h + ((size_t)h * NTOK + j) * DIM_HEAD + dbase);
        dst[0] = ((const uint4*)hv)[0];
        dst[1] = ((const uint4*)hv)[1];
    } else {
        // V stored transposed: vT[h][d][j]; per-u stores are 2B/lane, coalesced in j.
        #pragma unroll
        for (int u = 0; u < QKV_OT; ++u)
            vT_h[((size_t)h * DIM_HEAD + dbase + u) * NTOK + j] = (_Float16)acc[u];
    }
}

// -------------------- 4. Flash attention partial, fp16 MFMA, swapped QK^T ----
// Block = 4 waves; wave owns 16 queries; j-chunk = NTOK/JS = 1024 keys (16 tiles).
// QK^T computed SWAPPED (S^T = K.Q^T, same fragment reads, operands exchanged):
// lane holds one query q=(lane&15) with 16 key-scores in registers ->
// softmax reduce = 15 in-lane fmax + 2 shfl_xor (was 16 chained DS shuffles).
// P stored to per-wave LDS as packed b64 (4 stores/tile, was 16x 2B scalar).
// PV in round-7-verified orientation: acc D row=q=lg*4+r, col=d=la.
#define TJ 64
#define VPAD 72     // Vt / P LDS row stride in halves
__global__ __launch_bounds__(256)
void attn_mfma(const _Float16* __restrict__ q_h, const _Float16* __restrict__ k_h,
               const _Float16* __restrict__ vT_h,
               float* __restrict__ pm, float* __restrict__ pl,
               float* __restrict__ pacc) {
    const int tid = threadIdx.x;
    const int w = tid >> 6, lane = tid & 63;
    const int la = lane & 15, lg = lane >> 4;
    const int h = blockIdx.y;
    const int s = blockIdx.z;
    const int qbase = blockIdx.x * 64 + w * 16;
    const int jlen = NTOK / JS;          // 1024
    const int j0 = s * jlen;

    __shared__ _Float16 lk [2][TJ * DIM_HEAD];       // K tile
    __shared__ _Float16 lvt[2][DIM_HEAD * VPAD];     // V^T tile
    __shared__ _Float16 plds[4][16 * VPAD];          // per-wave P tile

    // Q fragment (row la = query, dims lg*8..+7), scale pre-baked.
    // Serves as the B operand of the swapped QK^T (B^T row la = Q row la).
    const half8 aq = *(const half8*)(q_h + ((size_t)h * NTOK + qbase + la) * DIM_HEAD + lg * 8);

    f32x4 acc0 = {0.f, 0.f, 0.f, 0.f};
    f32x4 acc1 = {0.f, 0.f, 0.f, 0.f};
    float m = -1e30f, l = 0.f;           // per-lane: query la

    const _Float16* kg = k_h  + (size_t)h * NTOK * DIM_HEAD + (size_t)j0 * DIM_HEAD;
    const _Float16* vg = vT_h + (size_t)h * DIM_HEAD * NTOK + j0;
    const int vrow = tid >> 3, vseg = tid & 7;       // V^T staging coords

    uint4 kreg, vreg;
    kreg = ((const uint4*)kg)[tid];
    vreg = *(const uint4*)(vg + (size_t)vrow * NTOK + vseg * 8);
    ((uint4*)lk[0])[tid] = kreg;
    *(uint4*)&lvt[0][vrow * VPAD + vseg * 8] = vreg;
    kreg = ((const uint4*)(kg + (size_t)TJ * DIM_HEAD))[tid];
    vreg = *(const uint4*)(vg + (size_t)vrow * NTOK + TJ + vseg * 8);
    __syncthreads();

    const int NT = jlen / TJ;     // 16
    for (int t = 0; t < NT; ++t) {
        const int cur = t & 1;
        if (t + 1 < NT) {
            ((uint4*)lk[cur ^ 1])[tid] = kreg;
            *(uint4*)&lvt[cur ^ 1][vrow * VPAD + vseg * 8] = vreg;
            if (t + 2 < NT) {
                kreg = ((const uint4*)(kg + (size_t)(t + 2) * TJ * DIM_HEAD))[tid];
                vreg = *(const uint4*)(vg + (size_t)vrow * NTOK + (t + 2) * TJ + vseg * 8);
            }
        }
        // ---- QK^T swapped: sc[sub][r] = S[key=sub*16+lg*4+r][q=la] ----
        f32x4 sc[4];
        #pragma unroll
        for (int sub = 0; sub < 4; ++sub) {
            const half8 ak = *(const half8*)&lk[cur][(sub * 16 + la) * DIM_HEAD + lg * 8];
            f32x4 z = {0.f, 0.f, 0.f, 0.f};
            sc[sub] = __builtin_amdgcn_mfma_f32_16x16x32_f16(ak, aq, z, 0, 0, 0);
        }
        // ---- per-lane max over 16 regs + 2-shfl cross-group reduce ----
        float tm = fmaxf(fmaxf(sc[0][0], sc[0][1]), fmaxf(sc[0][2], sc[0][3]));
        #pragma unroll
        for (int sub = 1; sub < 4; ++sub) {
            tm = fmaxf(tm, fmaxf(fmaxf(sc[sub][0], sc[sub][1]),
                                 fmaxf(sc[sub][2], sc[sub][3])));
        }
        tm = fmaxf(tm, __shfl_xor(tm, 16));
        tm = fmaxf(tm, __shfl_xor(tm, 32));
        const float mn   = fmaxf(m, tm);
        const float corr = __expf(m - mn);   // for query la
        m = mn;
        l *= corr;
        // rescale acc (acc row r belongs to query lg*4+r) with that query's corr
        #pragma unroll
        for (int r = 0; r < 4; ++r) {
            const float cq = __shfl(corr, lg * 4 + r);
            acc0[r] *= cq;
            acc1[r] *= cq;
        }
        // ---- probabilities: 16 exps, packed b64 stores into P[q][key] ----
        float ps = 0.f;
        #pragma unroll
        for (int sub = 0; sub < 4; ++sub) {
            union { _Float16 hp[4]; uint2 u; } pk;
            #pragma unroll
            for (int r = 0; r < 4; ++r) {
                const float p = __expf(sc[sub][r] - mn);
                ps += p;
                pk.hp[r] = (_Float16)p;
            }
            *(uint2*)&plds[w][la * VPAD + sub * 16 + lg * 4] = pk.u;
        }
        l += ps;
        // ---- PV: out[16q][32d] += P[16q][64k] * V[64k][32d] ----
        #pragma unroll
        for (int kc = 0; kc < 2; ++kc) {
            const half8 pa = *(const half8*)&plds[w][la * VPAD + kc * 32 + lg * 8];
            const half8 v0 = *(const half8*)&lvt[cur][(la     ) * VPAD + kc * 32 + lg * 8];
            const half8 v1 = *(const half8*)&lvt[cur][(la + 16) * VPAD + kc * 32 + lg * 8];
            acc0 = __builtin_amdgcn_mfma_f32_16x16x32_f16(pa, v0, acc0, 0, 0, 0);
            acc1 = __builtin_amdgcn_mfma_f32_16x16x32_f16(pa, v1, acc1, 0, 0, 0);
        }
        __syncthreads();
    }
    // ---- epilogue: reduce l across the 4 replicas, store raw partial state ----
    float lt = l;
    lt += __shfl_xor(lt, 16);
    lt += __shfl_xor(lt, 32);
    const size_t pbase = (size_t)(h * JS + s) * NTOK + qbase;
    if (lane < 16) {
        pm[pbase + la] = m;
        pl[pbase + la] = lt;
    }
    #pragma unroll
    for (int r = 0; r < 4; ++r) {
        const size_t pq = pbase + lg * 4 + r;
        pacc[pq * DIM_HEAD + la     ] = acc0[r];
        pacc[pq * DIM_HEAD + la + 16] = acc1[r];
    }
}

// -------------------- 5. Combine partial softmax states (JS=4) --------------------
__global__ void attn_combine4(const float* __restrict__ pm, const float* __restrict__ pl,
                              const float* __restrict__ pacc, float* __restrict__ att) {
    const int i = blockIdx.x * blockDim.x + threadIdx.x;   // 0..4095
    const int h = blockIdx.y;
    float mv[JS], lv[JS];
    float mM = -1e30f;
    #pragma unroll
    for (int s = 0; s < JS; ++s) {
        const size_t pidx = ((size_t)(h * JS + s) * NTOK + i);
        mv[s] = pm[pidx];
        lv[s] = pl[pidx];
        mM = fmaxf(mM, mv[s]);
    }
    float wv[JS];
    float denom = 0.f;
    #pragma unroll
    for (int s = 0; s < JS; ++s) {
        wv[s] = __expf(mv[s] - mM);
        denom += lv[s] * wv[s];
    }
    const float inv = 1.f / denom;
    #pragma unroll
    for (int d0 = 0; d0 < DIM_HEAD; d0 += 4) {
        float o0 = 0.f, o1 = 0.f, o2 = 0.f, o3 = 0.f;
        #pragma unroll
        for (int s = 0; s < JS; ++s) {
            const size_t pidx = ((size_t)(h * JS + s) * NTOK + i);
            float4 a = *(const float4*)(pacc + pidx * DIM_HEAD + d0);
            o0 = fmaf(a.x, wv[s], o0);
            o1 = fmaf(a.y, wv[s], o1);
            o2 = fmaf(a.z, wv[s], o2);
            o3 = fmaf(a.w, wv[s], o3);
        }
        att[(size_t)(h * DIM_HEAD + d0    ) * NTOK + i] = o0 * inv;
        att[(size_t)(h * DIM_HEAD + d0 + 1) * NTOK + i] = o1 * inv;
        att[(size_t)(h * DIM_HEAD + d0 + 2) * NTOK + i] = o2 * inv;
        att[(size_t)(h * DIM_HEAD + d0 + 3) * NTOK + i] = o3 * inv;
    }
}

// -------------------- 6. Output projection, 8 outputs/thread --------------------
#define OUT_OT 8
__global__ __launch_bounds__(256)
void out_proj(const float* __restrict__ att, const float* __restrict__ w,
              const float* __restrict__ b, const float* __restrict__ x,
              float* __restrict__ out) {
    const int j  = blockIdx.x * blockDim.x + threadIdx.x;  // 0..4095
    const int ob = blockIdx.y * OUT_OT;                    // 0..255 step 8
    float acc[OUT_OT];
    #pragma unroll
    for (int u = 0; u < OUT_OT; ++u) acc[u] = b[ob + u];
    for (int c = 0; c < CCH; c += 4) {
        const float a0 = att[(size_t)(c    ) * NTOK + j];
        const float a1 = att[(size_t)(c + 1) * NTOK + j];
        const float a2 = att[(size_t)(c + 2) * NTOK + j];
        const float a3 = att[(size_t)(c + 3) * NTOK + j];
        #pragma unroll
        for (int u = 0; u < OUT_OT; ++u) {
            const float* wr = w + (size_t)(ob + u) * CCH + c;  // wave-uniform -> s_load
            acc[u] = fmaf(wr[0], a0, acc[u]);
            acc[u] = fmaf(wr[1], a1, acc[u]);
            acc[u] = fmaf(wr[2], a2, acc[u]);
            acc[u] = fmaf(wr[3], a3, acc[u]);
        }
    }
    #pragma unroll
    for (int u = 0; u < OUT_OT; ++u) {
        const size_t idx = (size_t)(ob + u) * NTOK + j;
        out[idx] = acc[u] + x[idx];
    }
}

extern "C" void kernel_launch(void* const* d_in, const int* in_sizes, int n_in,
                              void* d_out, int out_size, void* d_ws, size_t ws_size,
                              hipStream_t stream) {
    const float* x     = (const float*)d_in[0];
    const float* gamma = (const float*)d_in[1];
    const float* beta  = (const float*)d_in[2];
    const float* w_qkv = (const float*)d_in[3];
    const float* b_qkv = (const float*)d_in[4];
    const float* w_out = (const float*)d_in[5];
    const float* b_out = (const float*)d_in[6];
    float* out = (float*)d_out;

    float* ws    = (float*)d_ws;
    float* stats = ws;                          // 64
    float* part  = stats + 64;                  // 512
    float* w2    = part  + 512;                 // 768*256 = 196608
    float* b2    = w2    + 196608;              // 768
    float* att   = b2    + 768;                 // 256*4096 = 1048576 (fp32)
    float* pm    = att   + 1048576;             // 8*4*4096 = 131072
    float* pl    = pm    + 131072;              // 131072
    float* pacc  = pl    + 131072;              // 8*4*4096*32 = 4194304 (16 MB)
    _Float16* q_h  = (_Float16*)(pacc + 4194304);          // 8*4096*32 halves (2MB)
    _Float16* k_h  = q_h + (size_t)HEADS * NTOK * DIM_HEAD;
    _Float16* vT_h = k_h + (size_t)HEADS * NTOK * DIM_HEAD;
    // total ~34 MB (ws proven >= 92 MB in round 2)

    {
        dim3 g(GN_SPLIT, GROUPS);
        gn_stats_partial<<<g, 256, 0, stream>>>(x, part);
    }
    gn_stats_final<<<GROUPS, 64, 0, stream>>>(part, stats);
    fold_qkv<<<3 * CCH, 256, 0, stream>>>(w_qkv, b_qkv, gamma, beta, stats, w2, b2);
    {
        dim3 g(NTOK / 256, 3 * CCH / QKV_OT);
        qkv_gemm<<<g, 256, 0, stream>>>(x, w2, b2, q_h, k_h, vT_h);
    }
    {
        dim3 g(NTOK / 64, HEADS, JS);
        attn_mfma<<<g, 256, 0, stream>>>(q_h, k_h, vT_h, pm, pl, pacc);
    }
    {
        dim3 g(NTOK / 256, HEADS);
        attn_combine4<<<g, 256, 0, stream>>>(pm, pl, pacc, att);
    }
    {
        dim3 g(NTOK / 256, CCH / OUT_OT);
        out_proj<<<g, 256, 0, stream>>>(att, w_out, b_out, x, out);
    }
}

// Round 9
// 130.862 us; speedup vs baseline: 4.1116x; 1.1972x over previous
//
#include <hip/hip_runtime.h>
#include <hip/hip_bf16.h>

#define HEADS 8
#define DIM_HEAD 32
#define GROUPS 8
#define CCH 256            // channels
#define NTOK 4096          // d*h*w = 16^3
#define EPS 1e-5f
#define GN_SPLIT 32
#define JS 4               // attention j-split (occupancy)

typedef _Float16 half8 __attribute__((ext_vector_type(8)));
typedef float f32x4 __attribute__((ext_vector_type(4)));

// -------------------- 1a. GroupNorm partial stats --------------------
__global__ void gn_stats_partial(const float* __restrict__ x, float* __restrict__ part) {
    const int g  = blockIdx.y;
    const int sp = blockIdx.x;
    const int M = (CCH / GROUPS) * NTOK;        // 131072 contiguous floats per group
    const int chunk = M / GN_SPLIT;             // 4096
    const float4* p = (const float4*)(x + (size_t)g * M + (size_t)sp * chunk);
    float s = 0.f, ss = 0.f;
    for (int i = threadIdx.x; i < chunk / 4; i += blockDim.x) {
        float4 v = p[i];
        s  += v.x + v.y + v.z + v.w;
        ss += v.x*v.x + v.y*v.y + v.z*v.z + v.w*v.w;
    }
    #pragma unroll
    for (int off = 32; off; off >>= 1) {
        s  += __shfl_down(s,  off);
        ss += __shfl_down(ss, off);
    }
    __shared__ float sh0[8], sh1[8];
    const int wave = threadIdx.x >> 6, lane = threadIdx.x & 63;
    if (lane == 0) { sh0[wave] = s; sh1[wave] = ss; }
    __syncthreads();
    if (threadIdx.x == 0) {
        float S = 0.f, SS = 0.f;
        const int nw = blockDim.x >> 6;
        for (int w = 0; w < nw; ++w) { S += sh0[w]; SS += sh1[w]; }
        part[(g * GN_SPLIT + sp) * 2]     = S;
        part[(g * GN_SPLIT + sp) * 2 + 1] = SS;
    }
}

// -------------------- 1b. GroupNorm finalize --------------------
__global__ void gn_stats_final(const float* __restrict__ part, float* __restrict__ stats) {
    const int g = blockIdx.x;           // 8 blocks, 64 threads
    float s = 0.f, ss = 0.f;
    if (threadIdx.x < GN_SPLIT) {
        s  = part[(g * GN_SPLIT + threadIdx.x) * 2];
        ss = part[(g * GN_SPLIT + threadIdx.x) * 2 + 1];
    }
    #pragma unroll
    for (int off = 16; off; off >>= 1) {
        s  += __shfl_down(s,  off);
        ss += __shfl_down(ss, off);
    }
    if (threadIdx.x == 0) {
        const int M = (CCH / GROUPS) * NTOK;
        const float mean = s / (float)M;
        const float var  = ss / (float)M - mean * mean;
        stats[g * 2]     = mean;
        stats[g * 2 + 1] = rsqrtf(var + EPS);
    }
}

// -------------------- 2. Fold GroupNorm into QKV weights --------------------
__global__ void fold_qkv(const float* __restrict__ w, const float* __restrict__ b,
                         const float* __restrict__ gamma, const float* __restrict__ beta,
                         const float* __restrict__ stats,
                         float* __restrict__ w2, float* __restrict__ b2) {
    const int o = blockIdx.x;           // 0..767
    const int c = threadIdx.x;          // 0..255
    const int g = c >> 5;
    const float mean = stats[g * 2];
    const float rstd = stats[g * 2 + 1];
    const float sc = gamma[c] * rstd;
    const float sh = beta[c] - mean * sc;
    const float wv = w[(size_t)o * CCH + c];
    w2[(size_t)o * CCH + c] = wv * sc;
    float t = wv * sh;
    #pragma unroll
    for (int off = 32; off; off >>= 1) t += __shfl_down(t, off);
    __shared__ float shred[4];
    const int wave = threadIdx.x >> 6, lane = threadIdx.x & 63;
    if (lane == 0) shred[wave] = t;
    __syncthreads();
    if (threadIdx.x == 0)
        b2[o] = b[o] + shred[0] + shred[1] + shred[2] + shred[3];
}

// -------------------- 3. QKV GEMM, software-pipelined, 8 outputs/thread ------
// R8 lesson: latency-bound (VALUBusy 17.6%, occ 26%) — loads were consumed
// immediately each c-step with no pipelining and only 3 blocks/CU. Fix:
// explicit next-chunk x prefetch (8 loads always in flight) + OT 16->8
// (grid 768->1536 blocks = 6 blocks/CU).
#define QKV_OT 8
__global__ __launch_bounds__(256)
void qkv_gemm(const float* __restrict__ x, const float* __restrict__ w,
              const float* __restrict__ b,
              _Float16* __restrict__ q_h, _Float16* __restrict__ k_h,
              _Float16* __restrict__ vT_h) {
    const int j  = blockIdx.x * blockDim.x + threadIdx.x;  // 0..4095
    const int ob = blockIdx.y * QKV_OT;                    // 0..767 step 8
    float acc[QKV_OT];
    #pragma unroll
    for (int u = 0; u < QKV_OT; ++u) acc[u] = b[ob + u];
    float xc[8], xn[8];
    #pragma unroll
    for (int u = 0; u < 8; ++u) xc[u] = x[(size_t)u * NTOK + j];
    for (int c = 0; c < CCH; c += 8) {
        if (c + 8 < CCH) {
            #pragma unroll
            for (int u = 0; u < 8; ++u) xn[u] = x[(size_t)(c + 8 + u) * NTOK + j];
        }
        #pragma unroll
        for (int v = 0; v < QKV_OT; ++v) {
            const float* wr = w + (size_t)(ob + v) * CCH + c;  // wave-uniform -> s_load
            #pragma unroll
            for (int u = 0; u < 8; ++u)
                acc[v] = fmaf(wr[u], xc[u], acc[v]);
        }
        #pragma unroll
        for (int u = 0; u < 8; ++u) xc[u] = xn[u];
    }
    const int part  = ob >> 8;
    const int h     = (ob & 255) >> 5;
    const int dbase = ob & 31;          // 0, 8, 16, 24
    if (part == 0) {
        const float scale = 0.17677669529663687f;  // 32^-0.5 baked into Q
        __attribute__((aligned(16))) _Float16 hv[QKV_OT];
        #pragma unroll
        for (int u = 0; u < QKV_OT; ++u) hv[u] = (_Float16)(acc[u] * scale);
        *(uint4*)(q_h + ((size_t)h * NTOK + j) * DIM_HEAD + dbase) = *(const uint4*)hv;
    } else if (part == 1) {
        __attribute__((aligned(16))) _Float16 hv[QKV_OT];
        #pragma unroll
        for (int u = 0; u < QKV_OT; ++u) hv[u] = (_Float16)acc[u];
        *(uint4*)(k_h + ((size_t)h * NTOK + j) * DIM_HEAD + dbase) = *(const uint4*)hv;
    } else {
        // V stored transposed: vT[h][d][j]; 2B/lane stores, coalesced in j.
        #pragma unroll
        for (int u = 0; u < QKV_OT; ++u)
            vT_h[((size_t)h * DIM_HEAD + dbase + u) * NTOK + j] = (_Float16)acc[u];
    }
}

// -------------------- 4. Flash attention partial, fp16 MFMA, swapped QK^T ----
// Block = 4 waves; wave owns 16 queries; j-chunk = NTOK/JS = 1024 keys (16 tiles).
// QK^T computed SWAPPED (S^T = K.Q^T): lane owns one query q=(lane&15) with 16
// key-scores in registers -> softmax reduce = in-lane fmax + 2 shfl_xor.
// P stored to per-wave LDS as packed b64. PV: acc D row=q=lg*4+r, col=d=la.
#define TJ 64
#define VPAD 72     // Vt / P LDS row stride in halves
__global__ __launch_bounds__(256)
void attn_mfma(const _Float16* __restrict__ q_h, const _Float16* __restrict__ k_h,
               const _Float16* __restrict__ vT_h,
               float* __restrict__ pm, float* __restrict__ pl,
               float* __restrict__ pacc) {
    const int tid = threadIdx.x;
    const int w = tid >> 6, lane = tid & 63;
    const int la = lane & 15, lg = lane >> 4;
    const int h = blockIdx.y;
    const int s = blockIdx.z;
    const int qbase = blockIdx.x * 64 + w * 16;
    const int jlen = NTOK / JS;          // 1024
    const int j0 = s * jlen;

    __shared__ _Float16 lk [2][TJ * DIM_HEAD];       // K tile
    __shared__ _Float16 lvt[2][DIM_HEAD * VPAD];     // V^T tile
    __shared__ _Float16 plds[4][16 * VPAD];          // per-wave P tile

    const half8 aq = *(const half8*)(q_h + ((size_t)h * NTOK + qbase + la) * DIM_HEAD + lg * 8);

    f32x4 acc0 = {0.f, 0.f, 0.f, 0.f};
    f32x4 acc1 = {0.f, 0.f, 0.f, 0.f};
    float m = -1e30f, l = 0.f;           // per-lane: query la

    const _Float16* kg = k_h  + (size_t)h * NTOK * DIM_HEAD + (size_t)j0 * DIM_HEAD;
    const _Float16* vg = vT_h + (size_t)h * DIM_HEAD * NTOK + j0;
    const int vrow = tid >> 3, vseg = tid & 7;       // V^T staging coords

    uint4 kreg, vreg;
    kreg = ((const uint4*)kg)[tid];
    vreg = *(const uint4*)(vg + (size_t)vrow * NTOK + vseg * 8);
    ((uint4*)lk[0])[tid] = kreg;
    *(uint4*)&lvt[0][vrow * VPAD + vseg * 8] = vreg;
    kreg = ((const uint4*)(kg + (size_t)TJ * DIM_HEAD))[tid];
    vreg = *(const uint4*)(vg + (size_t)vrow * NTOK + TJ + vseg * 8);
    __syncthreads();

    const int NT = jlen / TJ;     // 16
    for (int t = 0; t < NT; ++t) {
        const int cur = t & 1;
        if (t + 1 < NT) {
            ((uint4*)lk[cur ^ 1])[tid] = kreg;
            *(uint4*)&lvt[cur ^ 1][vrow * VPAD + vseg * 8] = vreg;
            if (t + 2 < NT) {
                kreg = ((const uint4*)(kg + (size_t)(t + 2) * TJ * DIM_HEAD))[tid];
                vreg = *(const uint4*)(vg + (size_t)vrow * NTOK + (t + 2) * TJ + vseg * 8);
            }
        }
        // ---- QK^T swapped: sc[sub][r] = S[key=sub*16+lg*4+r][q=la] ----
        f32x4 sc[4];
        #pragma unroll
        for (int sub = 0; sub < 4; ++sub) {
            const half8 ak = *(const half8*)&lk[cur][(sub * 16 + la) * DIM_HEAD + lg * 8];
            f32x4 z = {0.f, 0.f, 0.f, 0.f};
            sc[sub] = __builtin_amdgcn_mfma_f32_16x16x32_f16(ak, aq, z, 0, 0, 0);
        }
        // ---- per-lane max over 16 regs + 2-shfl cross-group reduce ----
        float tm = fmaxf(fmaxf(sc[0][0], sc[0][1]), fmaxf(sc[0][2], sc[0][3]));
        #pragma unroll
        for (int sub = 1; sub < 4; ++sub) {
            tm = fmaxf(tm, fmaxf(fmaxf(sc[sub][0], sc[sub][1]),
                                 fmaxf(sc[sub][2], sc[sub][3])));
        }
        tm = fmaxf(tm, __shfl_xor(tm, 16));
        tm = fmaxf(tm, __shfl_xor(tm, 32));
        const float mn   = fmaxf(m, tm);
        const float corr = __expf(m - mn);   // for query la
        m = mn;
        l *= corr;
        #pragma unroll
        for (int r = 0; r < 4; ++r) {
            const float cq = __shfl(corr, lg * 4 + r);
            acc0[r] *= cq;
            acc1[r] *= cq;
        }
        // ---- probabilities: 16 exps, packed b64 stores into P[q][key] ----
        float ps = 0.f;
        #pragma unroll
        for (int sub = 0; sub < 4; ++sub) {
            union { _Float16 hp[4]; uint2 u; } pk;
            #pragma unroll
            for (int r = 0; r < 4; ++r) {
                const float p = __expf(sc[sub][r] - mn);
                ps += p;
                pk.hp[r] = (_Float16)p;
            }
            *(uint2*)&plds[w][la * VPAD + sub * 16 + lg * 4] = pk.u;
        }
        l += ps;
        // ---- PV: out[16q][32d] += P[16q][64k] * V[64k][32d] ----
        #pragma unroll
        for (int kc = 0; kc < 2; ++kc) {
            const half8 pa = *(const half8*)&plds[w][la * VPAD + kc * 32 + lg * 8];
            const half8 v0 = *(const half8*)&lvt[cur][(la     ) * VPAD + kc * 32 + lg * 8];
            const half8 v1 = *(const half8*)&lvt[cur][(la + 16) * VPAD + kc * 32 + lg * 8];
            acc0 = __builtin_amdgcn_mfma_f32_16x16x32_f16(pa, v0, acc0, 0, 0, 0);
            acc1 = __builtin_amdgcn_mfma_f32_16x16x32_f16(pa, v1, acc1, 0, 0, 0);
        }
        __syncthreads();
    }
    // ---- epilogue: reduce l across the 4 replicas, store raw partial state ----
    float lt = l;
    lt += __shfl_xor(lt, 16);
    lt += __shfl_xor(lt, 32);
    const size_t pbase = (size_t)(h * JS + s) * NTOK + qbase;
    if (lane < 16) {
        pm[pbase + la] = m;
        pl[pbase + la] = lt;
    }
    #pragma unroll
    for (int r = 0; r < 4; ++r) {
        const size_t pq = pbase + lg * 4 + r;
        pacc[pq * DIM_HEAD + la     ] = acc0[r];
        pacc[pq * DIM_HEAD + la + 16] = acc1[r];
    }
}

// -------------------- 5. Combine partial softmax states (JS=4) --------------------
__global__ void attn_combine4(const float* __restrict__ pm, const float* __restrict__ pl,
                              const float* __restrict__ pacc, float* __restrict__ att) {
    const int i = blockIdx.x * blockDim.x + threadIdx.x;   // 0..4095
    const int h = blockIdx.y;
    float mv[JS], lv[JS];
    float mM = -1e30f;
    #pragma unroll
    for (int s = 0; s < JS; ++s) {
        const size_t pidx = ((size_t)(h * JS + s) * NTOK + i);
        mv[s] = pm[pidx];
        lv[s] = pl[pidx];
        mM = fmaxf(mM, mv[s]);
    }
    float wv[JS];
    float denom = 0.f;
    #pragma unroll
    for (int s = 0; s < JS; ++s) {
        wv[s] = __expf(mv[s] - mM);
        denom += lv[s] * wv[s];
    }
    const float inv = 1.f / denom;
    #pragma unroll
    for (int d0 = 0; d0 < DIM_HEAD; d0 += 4) {
        float o0 = 0.f, o1 = 0.f, o2 = 0.f, o3 = 0.f;
        #pragma unroll
        for (int s = 0; s < JS; ++s) {
            const size_t pidx = ((size_t)(h * JS + s) * NTOK + i);
            float4 a = *(const float4*)(pacc + pidx * DIM_HEAD + d0);
            o0 = fmaf(a.x, wv[s], o0);
            o1 = fmaf(a.y, wv[s], o1);
            o2 = fmaf(a.z, wv[s], o2);
            o3 = fmaf(a.w, wv[s], o3);
        }
        att[(size_t)(h * DIM_HEAD + d0    ) * NTOK + i] = o0 * inv;
        att[(size_t)(h * DIM_HEAD + d0 + 1) * NTOK + i] = o1 * inv;
        att[(size_t)(h * DIM_HEAD + d0 + 2) * NTOK + i] = o2 * inv;
        att[(size_t)(h * DIM_HEAD + d0 + 3) * NTOK + i] = o3 * inv;
    }
}

// -------------------- 6. Output projection, software-pipelined, 4 outputs/thread --
#define OUT_OT 4
__global__ __launch_bounds__(256)
void out_proj(const float* __restrict__ att, const float* __restrict__ w,
              const float* __restrict__ b, const float* __restrict__ x,
              float* __restrict__ out) {
    const int j  = blockIdx.x * blockDim.x + threadIdx.x;  // 0..4095
    const int ob = blockIdx.y * OUT_OT;                    // 0..255 step 4
    float acc[OUT_OT];
    #pragma unroll
    for (int u = 0; u < OUT_OT; ++u) acc[u] = b[ob + u];
    float ac[8], an[8];
    #pragma unroll
    for (int u = 0; u < 8; ++u) ac[u] = att[(size_t)u * NTOK + j];
    for (int c = 0; c < CCH; c += 8) {
        if (c + 8 < CCH) {
            #pragma unroll
            for (int u = 0; u < 8; ++u) an[u] = att[(size_t)(c + 8 + u) * NTOK + j];
        }
        #pragma unroll
        for (int v = 0; v < OUT_OT; ++v) {
            const float* wr = w + (size_t)(ob + v) * CCH + c;  // wave-uniform -> s_load
            #pragma unroll
            for (int u = 0; u < 8; ++u)
                acc[v] = fmaf(wr[u], ac[u], acc[v]);
        }
        #pragma unroll
        for (int u = 0; u < 8; ++u) ac[u] = an[u];
    }
    #pragma unroll
    for (int u = 0; u < OUT_OT; ++u) {
        const size_t idx = (size_t)(ob + u) * NTOK + j;
        out[idx] = acc[u] + x[idx];
    }
}

extern "C" void kernel_launch(void* const* d_in, const int* in_sizes, int n_in,
                              void* d_out, int out_size, void* d_ws, size_t ws_size,
                              hipStream_t stream) {
    const float* x     = (const float*)d_in[0];
    const float* gamma = (const float*)d_in[1];
    const float* beta  = (const float*)d_in[2];
    const float* w_qkv = (const float*)d_in[3];
    const float* b_qkv = (const float*)d_in[4];
    const float* w_out = (const float*)d_in[5];
    const float* b_out = (const float*)d_in[6];
    float* out = (float*)d_out;

    float* ws    = (float*)d_ws;
    float* stats = ws;                          // 64
    float* part  = stats + 64;                  // 512
    float* w2    = part  + 512;                 // 768*256 = 196608
    float* b2    = w2    + 196608;              // 768
    float* att   = b2    + 768;                 // 256*4096 = 1048576 (fp32)
    float* pm    = att   + 1048576;             // 8*4*4096 = 131072
    float* pl    = pm    + 131072;              // 131072
    float* pacc  = pl    + 131072;              // 8*4*4096*32 = 4194304 (16 MB)
    _Float16* q_h  = (_Float16*)(pacc + 4194304);          // 8*4096*32 halves (2MB)
    _Float16* k_h  = q_h + (size_t)HEADS * NTOK * DIM_HEAD;
    _Float16* vT_h = k_h + (size_t)HEADS * NTOK * DIM_HEAD;
    // total ~34 MB (ws proven >= 92 MB in round 2)

    {
        dim3 g(GN_SPLIT, GROUPS);
        gn_stats_partial<<<g, 256, 0, stream>>>(x, part);
    }
    gn_stats_final<<<GROUPS, 64, 0, stream>>>(part, stats);
    fold_qkv<<<3 * CCH, 256, 0, stream>>>(w_qkv, b_qkv, gamma, beta, stats, w2, b2);
    {
        dim3 g(NTOK / 256, 3 * CCH / QKV_OT);
        qkv_gemm<<<g, 256, 0, stream>>>(x, w2, b2, q_h, k_h, vT_h);
    }
    {
        dim3 g(NTOK / 64, HEADS, JS);
        attn_mfma<<<g, 256, 0, stream>>>(q_h, k_h, vT_h, pm, pl, pacc);
    }
    {
        dim3 g(NTOK / 256, HEADS);
        attn_combine4<<<g, 256, 0, stream>>>(pm, pl, pacc, att);
    }
    {
        dim3 g(NTOK / 256, CCH / OUT_OT);
        out_proj<<<g, 256, 0, stream>>>(att, w_out, b_out, x, out);
    }
}